// Round 16
// baseline (2396.176 us; speedup 1.0000x reference)
//
#include <hip/hip_runtime.h>
#include <stdint.h>

#define T_DIM 2048
#define B_DIM 1024
#define A_DIM 4
#define D_DIM 128
#define TC 32                   // steps per chunk (input readlane granularity)
#define HTC 16                  // steps per half-chunk (scan->GEMM granularity)
#define NCHUNK (T_DIM / TC)
#define LDH 136                 // Hb row stride in bf16 (68 dwords -> conflict-free b128)
#define LDC 136                 // Ct staging row stride
#define HB_BYTES (64 * LDH * 2)         // 17408 (64 rows: 4 waves x 16 steps)
// Qt pair-interleaved (r7 layout, halved): dword(col,slot) = (col>>1)*66 + 2*slot + (col&1)
//   32 slots (64 rows) + 1 pad pair -> stride 66; 64 colpairs x 66 = 4224 dw = 16896 B
// Writer: 2x 8B stores/group, same conflict-free bank-pair pattern as r7.
#define QT_S 66
// LDS high-water = init Ct staging (144*136*2 = 39168); Hb+Qt overlay = 34304 fits inside.
// 39168 B -> 4 blocks LDS-wise; VGPR cap via launch_bounds(256,3) -> 3 blocks/CU.
#define SMEM_BYTES (144 * LDC * 2)      // 39168

typedef __attribute__((ext_vector_type(8))) short bf16x8;
typedef __attribute__((ext_vector_type(4))) float f32x4;

__device__ __forceinline__ float clampf(float x, float lo, float hi) {
    return fminf(fmaxf(x, lo), hi);
}
__device__ __forceinline__ float sigclamp(float x) {
    return clampf(1.f / (1.f + __expf(-x)), 0.01f, 0.99f);
}
__device__ __forceinline__ uint16_t bf16rnd(float f) {
    uint32_t u = __builtin_bit_cast(uint32_t, f) + 0x8000u;   // round-nearest (ties away)
    return (uint16_t)(u >> 16);
}
// pack2(x,y) -> (bf16(y)<<16)|bf16(x) in 3 VALU ops (r10/r12/r14: packed-f32,
// cvt_pk intrinsic, setprio all neutral-to-worse; keep pack2)
__device__ __forceinline__ uint32_t pack2(float x, float y) {
    uint32_t ux = __builtin_bit_cast(uint32_t, x) + 0x8000u;
    uint32_t uy = __builtin_bit_cast(uint32_t, y) + 0x8000u;
    return __builtin_amdgcn_perm(uy, ux, 0x07060302);
}
__device__ __forceinline__ float bfLO(uint32_t u) {
    return __builtin_bit_cast(float, u << 16);
}
__device__ __forceinline__ float bfHI(uint32_t u) {
    return __builtin_bit_cast(float, u & 0xFFFF0000u);
}
template <int CTRL>
__device__ __forceinline__ float dppadd(float x) {
    int xi = __builtin_bit_cast(int, x);
    int yi = __builtin_amdgcn_mov_dpp(xi, CTRL, 0xF, 0xF, false);
    return x + __builtin_bit_cast(float, yi);
}
// sum across the 16 lanes of each DPP row (our ml-groups) via row_ror 1,2,4,8
__device__ __forceinline__ float rowsum16(float x) {
    x = dppadd<0x121>(x);
    x = dppadd<0x122>(x);
    x = dppadd<0x124>(x);
    x = dppadd<0x128>(x);
    return x;
}

// One block per b; 4 waves; wave wv owns action a=wv. No main-loop barriers
// (each wave only touches its own 16 Hb/Qt rows per half-chunk). Ct
// (B-fragments) in registers (144 regs) loaded once from LDS staging, then
// staging is overlaid by Hb/Qt.
//
// R16: 3 blocks/CU occupancy experiment, de-confounded from r6's spill:
//   - half-chunk tiling (scan 16 -> GEMM 1 m-tile, twice/chunk) halves Hb/Qt
//     so LDS high-water = 39168 B (3 blocks need <=53.3 KB) [r6's (a)]
//   - launch_bounds(256,3): VGPR cap 512/3~=170 >> the 128 this kernel uses,
//     so NO spill (r6's launch_bounds(256,4) cap of 64 was the disaster)
// Scaled-variable scan + beta'/C'/kappa' folds identical to the verified
// 530us r9 kernel.
__global__ __launch_bounds__(256, 3)
void gql_fused(const float* __restrict__ inp,
               const float* __restrict__ phi_raw,
               const float* __restrict__ chi_raw,
               const float* __restrict__ beta_raw,
               const float* __restrict__ kappa_raw,
               const float* __restrict__ C_raw,
               float* __restrict__ out)
{
    __shared__ __attribute__((aligned(16))) char smem[SMEM_BYTES];

    const int b    = blockIdx.x;
    const int tid  = threadIdx.x;
    const int lane = tid & 63;
    const int wv   = tid >> 6;
    const int ml   = lane & 15;
    const int qd   = lane >> 4;

    const int pid = (int)inp[(size_t)b * 9 + 8];

    // ---- scan params: thread owns (a=wv, d0=2*lane, d0+1)
    const int d0 = lane * 2;
    float2 pr = *(const float2*)(phi_raw + (size_t)pid * D_DIM + d0);
    float2 cr = *(const float2*)(chi_raw + (size_t)pid * D_DIM + d0);
    float phi0 = sigclamp(pr.x);
    float phi1 = sigclamp(pr.y);
    float chi0 = sigclamp(cr.x);
    float chi1 = sigclamp(cr.y);
    float omphi0 = 1.f - phi0, omphi1 = 1.f - phi1;
    float omchi0 = 1.f - chi0, omchi1 = 1.f - chi1;

    // ---- beta' = clamp(softplus(beta),.1,10) * phi_n (own sigmoid; init-only)
    float breg[9];
    #pragma unroll
    for (int nt = 0; nt < 8; ++nt) {
        float x = beta_raw[(size_t)pid * D_DIM + nt * 16 + ml];
        float p = sigclamp(phi_raw[(size_t)pid * D_DIM + nt * 16 + ml]);
        breg[nt] = clampf(log1pf(__expf(x)), 0.1f, 10.0f) * p;
    }
    breg[8] = 0.f;

    // ---- stage Ct[n=e][k=d] = bf16(chi_d * clip(C[d][e]) * phi_e)
    {
        uint16_t* Ct = (uint16_t*)smem;
        const float* Cp = C_raw + (size_t)pid * (D_DIM * D_DIM);
        // e = (i*256+tid)&127 = tid&127 (thread-invariant); d = 2i + (tid>>7)
        const float sphiE = sigclamp(phi_raw[(size_t)pid * D_DIM + (tid & 127)]);
        const int c0i = __builtin_bit_cast(int, chi0);
        const int c1i = __builtin_bit_cast(int, chi1);
        const int chsel = (tid >> 7) ? c1i : c0i;   // wave-uniform pick (d parity)
        #pragma unroll 8
        for (int i = 0; i < 64; ++i) {
            int idx = i * 256 + tid;
            int d = idx >> 7, e = idx & 127;
            float chD = __builtin_bit_cast(float, __builtin_amdgcn_readlane(chsel, i));
            Ct[e * LDC + d] = bf16rnd(clampf(Cp[idx], -10.f, 10.f) * chD * sphiE);
        }
        // kappa tile: zero-fill all except (n==0, k<128)
        for (int i = tid; i < 16 * LDC; i += 256) {
            int n = i / LDC;
            int k = i - n * LDC;
            if (!(n == 0 && k < D_DIM))
                Ct[(128 + n) * LDC + k] = 0;
        }
        // kappa' = clamp(kappa)*chi from wave 0's own regs (k0 = 2*tid)
        if (tid < 64) {
            float k0 = clampf(kappa_raw[(size_t)pid * D_DIM + 2 * tid], -10.f, 10.f);
            float k1 = clampf(kappa_raw[(size_t)pid * D_DIM + 2 * tid + 1], -10.f, 10.f);
            Ct[128 * LDC + 2 * tid]     = bf16rnd(k0 * chi0);
            Ct[128 * LDC + 2 * tid + 1] = bf16rnd(k1 * chi1);
        }
    }
    __syncthreads();

    // ---- B-fragments to registers (chunk-invariant): bfr[nt][kt]
    bf16x8 bfr[9][4];
    {
        const uint16_t* Ct = (const uint16_t*)smem;
        #pragma unroll
        for (int nt = 0; nt < 9; ++nt)
            #pragma unroll
            for (int kt = 0; kt < 4; ++kt)
                bfr[nt][kt] = *(const bf16x8*)&Ct[(nt * 16 + ml) * LDC + kt * 32 + qd * 8];
    }
    __syncthreads();   // staging area now dead; reuse as Hb/Qt

    uint32_t* H32 = (uint32_t*)smem;                    // Hb[m][k] bf16(v)-pairs, dword m*68+dpair (64 rows)
    uint32_t* Qt  = (uint32_t*)(smem + HB_BYTES);       // Qt pair-interleaved bf16(u), stride 66
    const uint16_t* Hb16 = (const uint16_t*)smem;

    // ---- per-chunk wave-uniform inputs via readlane: lane l<32 holds step l
    float actv, rav;
    {
        size_t t = (size_t)(lane & 31);
        const float* p = inp + (t * B_DIM + b) * 9;
        float a = p[wv], r = p[4 + wv];
        actv = a; rav = a * r;
    }

    const int qtw = lane * QT_S + wv * 16;  // Qt writer base (dwords): + (tlh-3) per group

    // scaled state: u = q/phi, v = h/chi  (q0 = 0.5, h0 = 0)
    float u0 = 0.5f / phi0, u1 = 0.5f / phi1, v0 = 0.f, v1 = 0.f;

    for (int chunk = 0; chunk < NCHUNK; ++chunk) {
        const int ai = __builtin_bit_cast(int, actv);
        const int ri = __builtin_bit_cast(int, rav);

        #pragma unroll
        for (int hf = 0; hf < 2; ++hf) {
            // ---- scan: 16 steps, 4 fma/step, register-only except LDS stores
            uint32_t hw_prev = 0, qwA0 = 0, qwA1 = 0;
            float u0p = 0.f, u1p = 0.f;
            #pragma unroll
            for (int tlh = 0; tlh < HTC; ++tlh) {
                const int tl = hf * HTC + tlh;
                float sa = __builtin_bit_cast(float, __builtin_amdgcn_readlane(ai, tl));
                float sr = __builtin_bit_cast(float, __builtin_amdgcn_readlane(ri, tl));
                u0 = fmaf(omphi0, u0, sr);
                u1 = fmaf(omphi1, u1, sr);
                v0 = fmaf(omchi0, v0, sa);
                v1 = fmaf(omchi1, v1, sa);
                uint32_t hw = pack2(v0, v1);
                if (tlh & 1) {
                    int m = wv * HTC + tlh - 1;
                    H32[m * 68 + lane] = hw_prev;       // rows m, m+1
                    H32[(m + 1) * 68 + lane] = hw;
                } else {
                    hw_prev = hw;
                }
                if ((tlh & 1) == 0) {
                    u0p = u0; u1p = u1;
                } else if ((tlh & 3) == 1) {
                    qwA0 = pack2(u0p, u0);              // col d0, slot s0
                    qwA1 = pack2(u1p, u1);              // col d0+1, slot s0
                } else {                                // tlh&3 == 3
                    uint32_t qwB0 = pack2(u0p, u0);     // slot s0+1
                    uint32_t qwB1 = pack2(u1p, u1);
                    uint32_t* qp = &Qt[qtw + (tlh - 3)];
                    *reinterpret_cast<uint2*>(qp)     = make_uint2(qwA0, qwA1);
                    *reinterpret_cast<uint2*>(qp + 2) = make_uint2(qwB0, qwB1);
                }
            }

            // prefetch next chunk's inputs after half 0 (hidden under GEMM+half 1)
            if (hf == 0 && chunk + 1 < NCHUNK) {
                size_t t = (size_t)(chunk + 1) * TC + (lane & 31);
                const float* p = inp + (t * B_DIM + b) * 9;
                float a = p[wv], r = p[4 + wv];
                actv = a; rav = a * r;
            }

            // ---- GEMM + epilogue: this wave's 16-row m-tile (mt == wv)
            f32x4 acc[9];
            #pragma unroll
            for (int nt = 0; nt < 9; ++nt)              // beta' folded into acc init
                acc[nt] = (f32x4){breg[nt], breg[nt], breg[nt], breg[nt]};

            #pragma unroll
            for (int kt = 0; kt < 4; ++kt) {
                bf16x8 afr = *(const bf16x8*)&Hb16[(size_t)(wv * HTC + ml) * LDH + kt * 32 + qd * 8];
                #pragma unroll
                for (int nt = 0; nt < 9; ++nt)
                    acc[nt] = __builtin_amdgcn_mfma_f32_16x16x32_bf16(afr, bfr[nt][kt], acc[nt], 0, 0, 0);
            }

            // kappa tile: col 128 lives at nt=8, ml==0; Q there == 1, beta' == 0
            bool km = (ml == 0);
            float p0 = km ? acc[8][0] : 0.f;
            float p1 = km ? acc[8][1] : 0.f;
            float p2 = km ? acc[8][2] : 0.f;
            float p3 = km ? acc[8][3] : 0.f;

            const int m2e = wv * 8 + qd * 2;            // slot of rows row0,row0+1
            // reader: col 16nt+ml -> colpair 8nt+(ml>>1), parity ml&1
            const uint32_t* qr = &Qt[(ml >> 1) * QT_S + (ml & 1) + 2 * m2e];
            #pragma unroll
            for (int nt = 0; nt < 8; ++nt) {
                uint32_t w0 = qr[nt * (8 * QT_S)];      // slot m2e
                uint32_t w1 = qr[nt * (8 * QT_S) + 2];  // slot m2e+1
                p0 = fmaf(acc[nt][0], bfLO(w0), p0);
                p1 = fmaf(acc[nt][1], bfHI(w0), p1);
                p2 = fmaf(acc[nt][2], bfLO(w1), p2);
                p3 = fmaf(acc[nt][3], bfHI(w1), p3);
            }

            p0 = rowsum16(p0);
            p1 = rowsum16(p1);
            p2 = rowsum16(p2);
            p3 = rowsum16(p3);

            if (ml == 0) {
                int r0 = qd * 4;
                #pragma unroll
                for (int r = 0; r < 4; ++r) {
                    size_t t = (size_t)chunk * TC + hf * HTC + r0 + r;
                    float pv = (r == 0) ? p0 : (r == 1) ? p1 : (r == 2) ? p2 : p3;
                    out[(t * B_DIM + b) * A_DIM + wv] = pv;
                }
            }
            // no barrier: next scan overwrites only this wave's own rows
            // after its own reads (same-wave LDS ordering)
        }
    }

    // ---- final q, h: rescale u,v back (phi = 1-omphi; <=1ulp vs original)
    float phr0 = 1.f - omphi0, phr1 = 1.f - omphi1;
    float chr0 = 1.f - omchi0, chr1 = 1.f - omchi1;
    size_t qbase = (size_t)T_DIM * B_DIM * A_DIM;
    size_t off = (size_t)b * (A_DIM * D_DIM) + (size_t)wv * D_DIM + d0;
    *(float2*)&out[qbase + off] = make_float2(phr0 * u0, phr1 * u1);
    *(float2*)&out[qbase + (size_t)B_DIM * A_DIM * D_DIM + off] = make_float2(chr0 * v0, chr1 * v1);
}

extern "C" void kernel_launch(void* const* d_in, const int* in_sizes, int n_in,
                              void* d_out, int out_size, void* d_ws, size_t ws_size,
                              hipStream_t stream) {
    const float* inp    = (const float*)d_in[0];
    const float* phi_r  = (const float*)d_in[1];
    const float* chi_r  = (const float*)d_in[2];
    const float* beta_r = (const float*)d_in[3];
    const float* kap_r  = (const float*)d_in[4];
    const float* C_r    = (const float*)d_in[5];
    float* outp = (float*)d_out;
    gql_fused<<<dim3(B_DIM), dim3(256), 0, stream>>>(inp, phi_r, chi_r, beta_r, kap_r, C_r, outp);
}

// Round 18
// 570.079 us; speedup vs baseline: 4.2032x; 4.2032x over previous
//
#include <hip/hip_runtime.h>
#include <stdint.h>

#define T_DIM 2048
#define B_DIM 1024
#define A_DIM 4
#define D_DIM 128
#define TC 32
#define NCHUNK (T_DIM / TC)
#define LDH 136                 // Hb row stride in bf16 elems (68 dwords == 4 mod 32 -> conflict-free b128)
#define LDC 136                 // Ct staging row stride
#define HB_BYTES (128 * LDH * 2)        // 34816
// Qt pair-interleaved: dword(col,slot) = (col>>1)*130 + 2*slot + (col&1)
// Writer: 2x 8B stores/group, 4 lanes per bank-pair = conflict-free (R7: -23% SQ_LDS_BANK_CONFLICT)
#define SMEM_BYTES (HB_BYTES + 64 * 130 * 4)   // 34816 + 33280 = 68096 (<80KB -> 2 blocks/CU)

typedef __attribute__((ext_vector_type(8))) short bf16x8;
typedef __attribute__((ext_vector_type(4))) float f32x4;

__device__ __forceinline__ float clampf(float x, float lo, float hi) {
    return fminf(fmaxf(x, lo), hi);
}
__device__ __forceinline__ float sigclamp(float x) {
    return clampf(1.f / (1.f + __expf(-x)), 0.01f, 0.99f);
}
__device__ __forceinline__ uint16_t bf16rnd(float f) {
    uint32_t u = __builtin_bit_cast(uint32_t, f) + 0x8000u;   // round-nearest (ties away)
    return (uint16_t)(u >> 16);
}
// pack2(x,y) -> (bf16(y)<<16)|bf16(x) in 3 VALU ops (r10/r12/r14: packed-f32,
// cvt_pk intrinsic, and setprio variants all measured neutral-to-worse)
__device__ __forceinline__ uint32_t pack2(float x, float y) {
    uint32_t ux = __builtin_bit_cast(uint32_t, x) + 0x8000u;
    uint32_t uy = __builtin_bit_cast(uint32_t, y) + 0x8000u;
    return __builtin_amdgcn_perm(uy, ux, 0x07060302);
}
__device__ __forceinline__ float bfLO(uint32_t u) {
    return __builtin_bit_cast(float, u << 16);
}
__device__ __forceinline__ float bfHI(uint32_t u) {
    return __builtin_bit_cast(float, u & 0xFFFF0000u);
}
template <int CTRL>
__device__ __forceinline__ float dppadd(float x) {
    int xi = __builtin_bit_cast(int, x);
    int yi = __builtin_amdgcn_mov_dpp(xi, CTRL, 0xF, 0xF, false);
    return x + __builtin_bit_cast(float, yi);
}
// sum across the 16 lanes of each DPP row (our ml-groups) via row_ror 1,2,4,8
__device__ __forceinline__ float rowsum16(float x) {
    x = dppadd<0x121>(x);
    x = dppadd<0x122>(x);
    x = dppadd<0x124>(x);
    x = dppadd<0x128>(x);
    return x;
}

// FINAL (session optimum, 530us verified twice; baseline was 577us).
//
// One block per b; 4 waves; wave wv owns action a=wv. No main-loop barriers
// (Qt/Hb producer-consumer is same-wave only). Ct (B-fragments) in registers
// (144 regs), loaded once from LDS staging then overlaid by Hb/Qt.
//
// Scaled-variable scan (u = q/phi, v = h/chi):
//   u' = (1-phi) u + r*a        v' = (1-chi) v + a     (4 fma/step, NO muls)
// Gains folded at init into staged operands:
//   C'[d][e] = chi_d*C[d][e]*phi_e, kappa'=kappa.chi, beta'=beta.phi (acc init)
//
// Occupancy is register-closed at 2 waves/SIMD: unified live set
// (bfr 144 + acc 36 + state ~50 ~= 230 regs) fits the 256-reg/2-wave cap but
// not the 170-reg/3-wave cap (r16: forcing 3 -> spill, 4.7GB scratch FETCH;
// r6: forcing 4 -> 8.2GB). Floor evidence: VALUBusy 60% + MfmaUtil 26%
// combined ~86% pipe occupancy; further counter-verified VALU/conflict cuts
// (r10/r12/r14) all converted to dependency stall, not time.
__global__ __launch_bounds__(256, 2)
void gql_fused(const float* __restrict__ inp,
               const float* __restrict__ phi_raw,
               const float* __restrict__ chi_raw,
               const float* __restrict__ beta_raw,
               const float* __restrict__ kappa_raw,
               const float* __restrict__ C_raw,
               float* __restrict__ out)
{
    __shared__ __attribute__((aligned(16))) char smem[SMEM_BYTES];

    const int b    = blockIdx.x;
    const int tid  = threadIdx.x;
    const int lane = tid & 63;
    const int wv   = tid >> 6;
    const int ml   = lane & 15;
    const int qd   = lane >> 4;

    const int pid = (int)inp[(size_t)b * 9 + 8];

    // ---- scan params: thread owns (a=wv, d0=2*lane, d0+1)
    const int d0 = lane * 2;
    float2 pr = *(const float2*)(phi_raw + (size_t)pid * D_DIM + d0);
    float2 cr = *(const float2*)(chi_raw + (size_t)pid * D_DIM + d0);
    float phi0 = sigclamp(pr.x);
    float phi1 = sigclamp(pr.y);
    float chi0 = sigclamp(cr.x);
    float chi1 = sigclamp(cr.y);
    float omphi0 = 1.f - phi0, omphi1 = 1.f - phi1;
    float omchi0 = 1.f - chi0, omchi1 = 1.f - chi1;

    // ---- beta' = clamp(softplus(beta),.1,10) * phi_n (own sigmoid; init-only)
    float breg[9];
    #pragma unroll
    for (int nt = 0; nt < 8; ++nt) {
        float x = beta_raw[(size_t)pid * D_DIM + nt * 16 + ml];
        float p = sigclamp(phi_raw[(size_t)pid * D_DIM + nt * 16 + ml]);
        breg[nt] = clampf(log1pf(__expf(x)), 0.1f, 10.0f) * p;
    }
    breg[8] = 0.f;

    // ---- stage Ct[n=e][k=d] = bf16(chi_d * clip(C[d][e]) * phi_e)
    {
        uint16_t* Ct = (uint16_t*)smem;
        const float* Cp = C_raw + (size_t)pid * (D_DIM * D_DIM);
        // e = (i*256+tid)&127 = tid&127 (thread-invariant); d = 2i + (tid>>7)
        const float sphiE = sigclamp(phi_raw[(size_t)pid * D_DIM + (tid & 127)]);
        const int c0i = __builtin_bit_cast(int, chi0);
        const int c1i = __builtin_bit_cast(int, chi1);
        const int chsel = (tid >> 7) ? c1i : c0i;   // wave-uniform pick (d parity)
        #pragma unroll 8
        for (int i = 0; i < 64; ++i) {
            int idx = i * 256 + tid;
            int d = idx >> 7, e = idx & 127;
            float chD = __builtin_bit_cast(float, __builtin_amdgcn_readlane(chsel, i));
            Ct[e * LDC + d] = bf16rnd(clampf(Cp[idx], -10.f, 10.f) * chD * sphiE);
        }
        // kappa tile: zero-fill all except (n==0, k<128)
        for (int i = tid; i < 16 * LDC; i += 256) {
            int n = i / LDC;
            int k = i - n * LDC;
            if (!(n == 0 && k < D_DIM))
                Ct[(128 + n) * LDC + k] = 0;
        }
        // kappa' = clamp(kappa)*chi from wave 0's own regs (k0 = 2*tid)
        if (tid < 64) {
            float k0 = clampf(kappa_raw[(size_t)pid * D_DIM + 2 * tid], -10.f, 10.f);
            float k1 = clampf(kappa_raw[(size_t)pid * D_DIM + 2 * tid + 1], -10.f, 10.f);
            Ct[128 * LDC + 2 * tid]     = bf16rnd(k0 * chi0);
            Ct[128 * LDC + 2 * tid + 1] = bf16rnd(k1 * chi1);
        }
    }
    __syncthreads();

    // ---- B-fragments to registers (chunk-invariant): bfr[nt][kt]
    bf16x8 bfr[9][4];
    {
        const uint16_t* Ct = (const uint16_t*)smem;
        #pragma unroll
        for (int nt = 0; nt < 9; ++nt)
            #pragma unroll
            for (int kt = 0; kt < 4; ++kt)
                bfr[nt][kt] = *(const bf16x8*)&Ct[(nt * 16 + ml) * LDC + kt * 32 + qd * 8];
    }
    __syncthreads();   // staging area now dead; reuse as Hb/Qt

    uint32_t* H32 = (uint32_t*)smem;                    // Hb[m][k] = bf16(v)-pairs, dword idx m*68+dpair
    uint32_t* Qt  = (uint32_t*)(smem + HB_BYTES);       // Qt pair-interleaved bf16(u) (see top)
    const uint16_t* Hb16 = (const uint16_t*)smem;

    // ---- per-chunk wave-uniform inputs via readlane: lane l<32 holds step l
    float actv, rav;
    {
        size_t t = (size_t)(lane & 31);
        const float* p = inp + (t * B_DIM + b) * 9;
        float a = p[wv], r = p[4 + wv];
        actv = a; rav = a * r;
    }

    const int qtw = lane * 130 + wv * 32;   // Qt writer base (dwords): + (tl-3) per group

    // scaled state: u = q/phi, v = h/chi  (q0 = 0.5, h0 = 0)
    float u0 = 0.5f / phi0, u1 = 0.5f / phi1, v0 = 0.f, v1 = 0.f;

    for (int chunk = 0; chunk < NCHUNK; ++chunk) {
        const int ai = __builtin_bit_cast(int, actv);
        const int ri = __builtin_bit_cast(int, rav);

        // ---- scan: 32 steps, 4 fma/step, register-only except paired LDS stores
        uint32_t hw_prev = 0, qwA0 = 0, qwA1 = 0;
        float u0p = 0.f, u1p = 0.f;
        #pragma unroll
        for (int tl = 0; tl < TC; ++tl) {
            float sa = __builtin_bit_cast(float, __builtin_amdgcn_readlane(ai, tl));
            float sr = __builtin_bit_cast(float, __builtin_amdgcn_readlane(ri, tl));
            u0 = fmaf(omphi0, u0, sr);
            u1 = fmaf(omphi1, u1, sr);
            v0 = fmaf(omchi0, v0, sa);
            v1 = fmaf(omchi1, v1, sa);
            uint32_t hw = pack2(v0, v1);
            if (tl & 1) {
                int m = wv * TC + tl - 1;
                H32[m * 68 + lane] = hw_prev;           // rows m, m+1: ds_write2-mergeable
                H32[(m + 1) * 68 + lane] = hw;
            } else {
                hw_prev = hw;
            }
            if ((tl & 1) == 0) {
                u0p = u0; u1p = u1;
            } else if ((tl & 3) == 1) {
                qwA0 = pack2(u0p, u0);                  // col d0, rows tl-1,tl
                qwA1 = pack2(u1p, u1);                  // col d0+1
            } else {                                    // tl&3 == 3
                uint32_t qwB0 = pack2(u0p, u0);
                uint32_t qwB1 = pack2(u1p, u1);
                uint32_t* qp = &Qt[qtw + (tl - 3)];
                *reinterpret_cast<uint2*>(qp)     = make_uint2(qwA0, qwA1);
                *reinterpret_cast<uint2*>(qp + 2) = make_uint2(qwB0, qwB1);
            }
        }

        // prefetch next chunk's inputs (latency hidden behind GEMM+epilogue)
        if (chunk + 1 < NCHUNK) {
            size_t t = (size_t)(chunk + 1) * TC + (lane & 31);
            const float* p = inp + (t * B_DIM + b) * 9;
            float a = p[wv], r = p[4 + wv];
            actv = a; rav = a * r;
        }

        // ---- GEMM + epilogue, one 16-row m-tile at a time (acc regs halved)
        #pragma unroll
        for (int mi = 0; mi < 2; ++mi) {
            const int mt = wv * 2 + mi;
            f32x4 acc[9];
            #pragma unroll
            for (int nt = 0; nt < 9; ++nt)              // beta' folded into acc init
                acc[nt] = (f32x4){breg[nt], breg[nt], breg[nt], breg[nt]};

            #pragma unroll
            for (int kt = 0; kt < 4; ++kt) {
                bf16x8 afr = *(const bf16x8*)&Hb16[(size_t)(mt * 16 + ml) * LDH + kt * 32 + qd * 8];
                #pragma unroll
                for (int nt = 0; nt < 9; ++nt)
                    acc[nt] = __builtin_amdgcn_mfma_f32_16x16x32_bf16(afr, bfr[nt][kt], acc[nt], 0, 0, 0);
            }

            // kappa tile: col 128 lives at nt=8, ml==0; Q there == 1, beta' == 0
            bool km = (ml == 0);
            float p0 = km ? acc[8][0] : 0.f;
            float p1 = km ? acc[8][1] : 0.f;
            float p2 = km ? acc[8][2] : 0.f;
            float p3 = km ? acc[8][3] : 0.f;

            const int m2e = mt * 8 + qd * 2;            // global row-pair of rows row0,row0+1
            // reader base: col 16nt+ml -> colpair 8nt+(ml>>1), parity ml&1
            const uint32_t* qr = &Qt[(ml >> 1) * 130 + (ml & 1) + 2 * m2e];
            #pragma unroll
            for (int nt = 0; nt < 8; ++nt) {
                uint32_t w0 = qr[nt * 1040];            // slot m2e   (rows row0,row0+1)
                uint32_t w1 = qr[nt * 1040 + 2];        // slot m2e+1 (rows row0+2,row0+3)
                p0 = fmaf(acc[nt][0], bfLO(w0), p0);
                p1 = fmaf(acc[nt][1], bfHI(w0), p1);
                p2 = fmaf(acc[nt][2], bfLO(w1), p2);
                p3 = fmaf(acc[nt][3], bfHI(w1), p3);
            }

            p0 = rowsum16(p0);
            p1 = rowsum16(p1);
            p2 = rowsum16(p2);
            p3 = rowsum16(p3);

            if (ml == 0) {
                int row0 = mt * 16 + qd * 4;
                #pragma unroll
                for (int r = 0; r < 4; ++r) {
                    int row = row0 + r;
                    int aa = row >> 5;
                    int tl = row & (TC - 1);
                    size_t t = (size_t)chunk * TC + tl;
                    float pv = (r == 0) ? p0 : (r == 1) ? p1 : (r == 2) ? p2 : p3;
                    out[(t * B_DIM + b) * A_DIM + aa] = pv;
                }
            }
        }
        // no barrier: next scan overwrites only this wave's own rows after its own reads
    }

    // ---- final q, h: rescale u,v back (phi = 1-omphi; <=1ulp vs original)
    float phr0 = 1.f - omphi0, phr1 = 1.f - omphi1;
    float chr0 = 1.f - omchi0, chr1 = 1.f - omchi1;
    size_t qbase = (size_t)T_DIM * B_DIM * A_DIM;
    size_t off = (size_t)b * (A_DIM * D_DIM) + (size_t)wv * D_DIM + d0;
    *(float2*)&out[qbase + off] = make_float2(phr0 * u0, phr1 * u1);
    *(float2*)&out[qbase + (size_t)B_DIM * A_DIM * D_DIM + off] = make_float2(chr0 * v0, chr1 * v1);
}

extern "C" void kernel_launch(void* const* d_in, const int* in_sizes, int n_in,
                              void* d_out, int out_size, void* d_ws, size_t ws_size,
                              hipStream_t stream) {
    const float* inp    = (const float*)d_in[0];
    const float* phi_r  = (const float*)d_in[1];
    const float* chi_r  = (const float*)d_in[2];
    const float* beta_r = (const float*)d_in[3];
    const float* kap_r  = (const float*)d_in[4];
    const float* C_r    = (const float*)d_in[5];
    float* outp = (float*)d_out;
    gql_fused<<<dim3(B_DIM), dim3(256), 0, stream>>>(inp, phi_r, chi_r, beta_r, kap_r, C_r, outp);
}